// Round 6
// baseline (435.489 us; speedup 1.0000x reference)
//
#include <hip/hip_runtime.h>
#include <stdint.h>

#define NB 4
#define CCH 256
#define HW 4096
#define HEADS 4
#define DH 64
#define SLEN 4096
#define EPSV 1e-5f
#define NEG_INF (-__builtin_inff())
#define QSCALE (0.125f * 1.44269504088896340736f)

typedef unsigned short u16;
typedef __bf16 bf16x8 __attribute__((ext_vector_type(8)));
typedef float f32x4 __attribute__((ext_vector_type(4)));

__device__ __forceinline__ u16 f2bf(float f) {
  union { float f; uint32_t u; } v; v.f = f;
  uint32_t r = v.u + 0x7FFFu + ((v.u >> 16) & 1u);
  return (u16)(r >> 16);
}

// ---------------- fused BN stats (blocks 0..255) + weight cvt (blocks 256..383) ----
__global__ __launch_bounds__(256) void k_pre(
    const float* __restrict__ x, const float* __restrict__ gamma,
    const float* __restrict__ beta, const float* __restrict__ qw,
    const float* __restrict__ pw, float* __restrict__ ab,
    u16* __restrict__ qwb, u16* __restrict__ pwb) {
  int t = threadIdx.x;
  if (blockIdx.x < 256) {
    int ch = blockIdx.x;
    float s = 0.f, ss = 0.f;
    for (int n = 0; n < NB; ++n) {
      const float4* p = (const float4*)(x + ((size_t)(n * CCH + ch)) * HW);
      for (int i = t; i < HW / 4; i += 256) {
        float4 v = p[i];
        s += v.x + v.y + v.z + v.w;
        ss += v.x * v.x + v.y * v.y + v.z * v.z + v.w * v.w;
      }
    }
#pragma unroll
    for (int mm = 32; mm >= 1; mm >>= 1) {
      s += __shfl_down(s, mm);
      ss += __shfl_down(ss, mm);
    }
    __shared__ float ls[4], lss[4];
    if ((t & 63) == 0) { ls[t >> 6] = s; lss[t >> 6] = ss; }
    __syncthreads();
    if (t == 0) {
      float S = 0.f, SS = 0.f;
      for (int i = 0; i < 4; ++i) { S += ls[i]; SS += lss[i]; }
      float inv = 1.0f / (float)(NB * HW);
      float mean = S * inv;
      float var = SS * inv - mean * mean;
      float a = gamma[ch] * rsqrtf(var + EPSV);
      ab[ch] = a;
      ab[CCH + ch] = beta[ch] - mean * a;
    }
  } else {
    const int NQ = CCH * 3 * CCH;  // 196608
    int i = ((blockIdx.x - 256) * 256 + t) * 8;
    const float* src = (i < NQ) ? (qw + i) : (pw + (i - NQ));
    u16* dst = (i < NQ) ? (qwb + i) : (pwb + (i - NQ));
    float4 v0 = *(const float4*)src;
    float4 v1 = *(const float4*)(src + 4);
    union { u16 u[8]; uint4 v; } o;
    o.u[0] = f2bf(v0.x); o.u[1] = f2bf(v0.y); o.u[2] = f2bf(v0.z); o.u[3] = f2bf(v0.w);
    o.u[4] = f2bf(v1.x); o.u[5] = f2bf(v1.y); o.u[6] = f2bf(v1.z); o.u[7] = f2bf(v1.w);
    *(uint4*)dst = o.v;
  }
}

// ---------------- normalize + transpose -> seq bf16 (n, hw, c) ----------------
__global__ __launch_bounds__(256) void k_seq(
    const float* __restrict__ x, const float* __restrict__ ab,
    u16* __restrict__ seq) {
  __shared__ float tile[64][65];
  int pb = blockIdx.x * 64, cb = blockIdx.y * 64, n = blockIdx.z;
  int t = threadIdx.x;
  {
    int cl = t >> 2, pc = (t & 3) * 16;
    float a = ab[cb + cl], b = ab[CCH + cb + cl];
    const float* src = x + ((size_t)(n * CCH + cb + cl)) * HW + pb + pc;
#pragma unroll
    for (int i = 0; i < 4; ++i) {
      float4 v = *(const float4*)(src + i * 4);
      tile[cl][pc + i * 4 + 0] = v.x * a + b;
      tile[cl][pc + i * 4 + 1] = v.y * a + b;
      tile[cl][pc + i * 4 + 2] = v.z * a + b;
      tile[cl][pc + i * 4 + 3] = v.w * a + b;
    }
  }
  __syncthreads();
  {
    int pl = t >> 2, cs = (t & 3) * 16;
    union { u16 u[16]; uint4 v[2]; } tmp;
#pragma unroll
    for (int i = 0; i < 16; ++i) tmp.u[i] = f2bf(tile[cs + i][pl]);
    u16* dst = seq + ((size_t)(n * HW + pb + pl)) * CCH + cb + cs;
    *(uint4*)dst = tmp.v[0];
    *(uint4*)(dst + 8) = tmp.v[1];
  }
}

// ---------------- QKV GEMM -> scatter Q(scaled)/K/Vt ----------------
__global__ __launch_bounds__(256) void k_qkv(
    const u16* __restrict__ seq, const u16* __restrict__ w,
    u16* __restrict__ Q, u16* __restrict__ K, u16* __restrict__ Vt) {
  __shared__ __attribute__((aligned(16))) u16 As[64 * 32];
  __shared__ __attribute__((aligned(16))) u16 Bs[64 * 32];
  int Rb = blockIdx.x * 64, Cb = blockIdx.y * 64;
  int t = threadIdx.x, lane = t & 63, wv = t >> 6;
  int wr = (wv >> 1) * 32, wc = (wv & 1) * 32;
  f32x4 acc[2][2] = {};
  for (int kb = 0; kb < CCH; kb += 32) {
    {
      int r = t >> 2, kc = t & 3;
      uint4 v = *(const uint4*)(seq + ((size_t)(Rb + r)) * CCH + kb + kc * 8);
      *(uint4*)((char*)As + r * 64 + ((kc * 16) ^ ((r & 3) << 4))) = v;
    }
    {
      int k = t >> 3, jc = (t & 7) * 8;
      union { u16 u[8]; uint4 v; } tmp;
      tmp.v = *(const uint4*)(w + ((size_t)(kb + k)) * 768 + Cb + jc);
#pragma unroll
      for (int i2 = 0; i2 < 8; ++i2) {
        int j = jc + i2;
        *(u16*)((char*)Bs + j * 64 + ((k * 2) ^ ((j & 3) << 4))) = tmp.u[i2];
      }
    }
    __syncthreads();
    bf16x8 af[2], bfr[2];
#pragma unroll
    for (int f = 0; f < 2; ++f) {
      int row = wr + f * 16 + (lane & 15);
      af[f] = *(const bf16x8*)((const char*)As + row * 64 +
                               (((lane >> 4) * 16) ^ ((row & 3) << 4)));
      int col = wc + f * 16 + (lane & 15);
      bfr[f] = *(const bf16x8*)((const char*)Bs + col * 64 +
                                (((lane >> 4) * 16) ^ ((col & 3) << 4)));
    }
#pragma unroll
    for (int i2 = 0; i2 < 2; ++i2)
#pragma unroll
      for (int j2 = 0; j2 < 2; ++j2)
        acc[i2][j2] = __builtin_amdgcn_mfma_f32_16x16x32_bf16(af[i2], bfr[j2], acc[i2][j2], 0, 0, 0);
    __syncthreads();
  }
#pragma unroll
  for (int i2 = 0; i2 < 2; ++i2)
#pragma unroll
    for (int j2 = 0; j2 < 2; ++j2)
#pragma unroll
      for (int e = 0; e < 4; ++e) {
        int R = Rb + wr + i2 * 16 + (lane >> 4) * 4 + e;
        int cg = Cb + wc + j2 * 16 + (lane & 15);
        int p = R & (HW - 1);
        int head = p >> 10, mq = p & 1023;
        int qn = mq * 4 + cg / 192, tt = cg % 192;
        int nhx = (R >> 12) * HEADS + head;
        float a = acc[i2][j2][e];
        if (tt < 64)
          Q[((size_t)nhx * SLEN + qn) * DH + tt] = f2bf(a * QSCALE);
        else if (tt < 128)
          K[((size_t)nhx * SLEN + qn) * DH + tt - 64] = f2bf(a);
        else
          Vt[(size_t)nhx * SLEN * DH + (size_t)(tt - 128) * SLEN + qn] = f2bf(a);
      }
}

// ---------------- flash attention: 4 waves, kv-split 4 ----------------
// Same-register software pipeline: loadK(t+1) right after qksoft consumes kf
// (load-use distance = pv's 32 MFMAs); loadV(t+1) after pv consumes vf
// (distance = next tile's qksoft). No double-buffer -> no spills.
// Gate-first softmax: in-lane st-max tree, __any gate BEFORE any exp work;
// common path has zero cross-lane ops.
__global__ __launch_bounds__(256, 2) void k_attn(
    const u16* __restrict__ Q, const u16* __restrict__ K,
    const u16* __restrict__ Vt, u16* __restrict__ O) {
  __shared__ __attribute__((aligned(16))) char smem[32768 + 2048];
  float* mlA = (float*)(smem + 32768);         // [slot4][qf4][row16] m
  float* mlB = (float*)(smem + 32768 + 1024);  // [slot4][qf4][row16] l
  // XCD-chunked swizzle: each XCD gets a contiguous 128-block chunk
  // (= 2 heads' K/V -> fits its 4MB L2). Verified: FETCH 70->20 MB.
  int bid = blockIdx.x;
  int wid = (bid & 7) * 128 + (bid >> 3);
  int nh = wid >> 6;
  int q0 = (wid & 63) * 64;
  int t = threadIdx.x, lane = t & 63, w = t >> 6;
  int l15 = lane & 15, g = lane >> 4;
  size_t base = (size_t)nh * SLEN * DH;
  char* Ps = smem + w * 8192;  // [64 q][64 kv] bf16, swizzled
  int swz = (l15 & 7) << 4;

  // Q fragments (B-operand: col = q = l15, k = d)
  bf16x8 qv[4][2];
#pragma unroll
  for (int qf = 0; qf < 4; ++qf) {
    const u16* qp = Q + base + (size_t)(q0 + qf * 16 + l15) * DH + g * 8;
    qv[qf][0] = *(const bf16x8*)qp;
    qv[qf][1] = *(const bf16x8*)(qp + 32);
  }

  f32x4 o[4][4] = {};
  float m[4] = {NEG_INF, NEG_INF, NEG_INF, NEG_INF};
  float lsum[4] = {0.f, 0.f, 0.f, 0.f};

  const u16* Kptr = K + base + (size_t)l15 * DH + g * 8;
  const u16* Vptr = Vt + base + (size_t)l15 * SLEN + g * 8;

  bf16x8 kf[4][2], vf[4][2];

  auto loadK = [&](int kv0) {
#pragma unroll
    for (int cf = 0; cf < 4; ++cf) {
      const u16* kp = Kptr + (size_t)(kv0 + cf * 16) * DH;
      kf[cf][0] = *(const bf16x8*)kp;
      kf[cf][1] = *(const bf16x8*)(kp + 32);
    }
  };
  auto loadV = [&](int kv0) {
#pragma unroll
    for (int df = 0; df < 4; ++df) {
      const u16* vp = Vptr + (size_t)(df * 16) * SLEN + kv0;
      vf[df][0] = *(const bf16x8*)vp;
      vf[df][1] = *(const bf16x8*)(vp + 32);
    }
  };

  auto qksoft = [&]() {
#pragma unroll
    for (int qf = 0; qf < 4; ++qf) {
      f32x4 st[4];
      __builtin_amdgcn_s_setprio(1);
#pragma unroll
      for (int cf = 0; cf < 4; ++cf) {
        f32x4 a = {};
        a = __builtin_amdgcn_mfma_f32_16x16x32_bf16(kf[cf][0], qv[qf][0], a, 0, 0, 0);
        a = __builtin_amdgcn_mfma_f32_16x16x32_bf16(kf[cf][1], qv[qf][1], a, 0, 0, 0);
        st[cf] = a;
      }
      __builtin_amdgcn_s_setprio(0);
      // in-lane max of the 16 st values (fmax tree, no cross-lane)
      float mx0 = fmaxf(fmaxf(st[0][0], st[0][1]), fmaxf(st[0][2], st[0][3]));
      float mx1 = fmaxf(fmaxf(st[1][0], st[1][1]), fmaxf(st[1][2], st[1][3]));
      float mx2 = fmaxf(fmaxf(st[2][0], st[2][1]), fmaxf(st[2][2], st[2][3]));
      float mx3 = fmaxf(fmaxf(st[3][0], st[3][1]), fmaxf(st[3][2], st[3][3]));
      float stmax = fmaxf(fmaxf(mx0, mx1), fmaxf(mx2, mx3));
      // gate BEFORE exp work; rare path (first tile + material max growth)
      if (__any(stmax > m[qf] + 8.0f)) {
        float mx = fmaxf(stmax, __shfl_xor(stmax, 16));
        mx = fmaxf(mx, __shfl_xor(mx, 32));
        float mn = fmaxf(m[qf], mx);
        float al = exp2f(m[qf] - mn);
        m[qf] = mn;
        lsum[qf] *= al;
#pragma unroll
        for (int e = 0; e < 4; ++e) {
          float ae = __shfl(al, (lane & 48) | (((lane >> 4) << 2) + e));
#pragma unroll
          for (int df = 0; df < 4; ++df) o[qf][df][e] *= ae;
        }
      }
      float mq = m[qf];
      f32x4 lsv = {0.f, 0.f, 0.f, 0.f};
#pragma unroll
      for (int cf = 0; cf < 4; ++cf) {
        union { __bf16 h[4]; uint2 v; } pk;
#pragma unroll
        for (int e = 0; e < 4; ++e) {
          float p = exp2f(st[cf][e] - mq);
          lsv[e] += p;
          pk.h[e] = (__bf16)p;
        }
        *(uint2*)(Ps + (qf * 16 + l15) * 128 + ((cf * 32 + g * 8) ^ swz)) = pk.v;
      }
      lsum[qf] += lsv[0] + lsv[1] + lsv[2] + lsv[3];
    }
  };

  auto pv = [&]() {
#pragma unroll
    for (int qf = 0; qf < 4; ++qf) {
#pragma unroll
      for (int ks = 0; ks < 2; ++ks) {
        bf16x8 pa = *(const bf16x8*)(Ps + (qf * 16 + l15) * 128 + ((ks * 64 + g * 16) ^ swz));
        __builtin_amdgcn_s_setprio(1);
#pragma unroll
        for (int df = 0; df < 4; ++df)
          o[qf][df] = __builtin_amdgcn_mfma_f32_16x16x32_bf16(pa, vf[df][ks], o[qf][df], 0, 0, 0);
        __builtin_amdgcn_s_setprio(0);
      }
    }
  };

  const int TILES = SLEN / 64 / 4;  // 16 per wave
  int kvBase = w * TILES * 64;
  loadK(kvBase);
  loadV(kvBase);
  for (int tt = 0; tt < TILES; ++tt) {
    int nxt = (tt + 1 < TILES) ? (kvBase + (tt + 1) * 64) : kvBase;
    qksoft();     // consumes kf
    loadK(nxt);   // refill kf; use distance = pv below
    pv();         // consumes vf
    loadV(nxt);   // refill vf; use distance = next qksoft
  }

  // finalize per-wave state: reduce l across g, convert m/l to C-frag layout
#pragma unroll
  for (int qf = 0; qf < 4; ++qf) {
    lsum[qf] += __shfl_xor(lsum[qf], 16);
    lsum[qf] += __shfl_xor(lsum[qf], 32);
  }
  f32x4 me[4], le[4];
#pragma unroll
  for (int qf = 0; qf < 4; ++qf)
#pragma unroll
    for (int e = 0; e < 4; ++e) {
      int idx = (lane & 48) | (((lane >> 4) & 3) << 2) | e;
      me[qf][e] = __shfl(m[qf], idx);
      le[qf][e] = __shfl(lsum[qf], idx);
    }

  auto publish = [&](char* reg, int s) {
#pragma unroll
    for (int qf = 0; qf < 4; ++qf) {
#pragma unroll
      for (int df = 0; df < 4; ++df) {
        int d = df * 16 + l15;
        *(f32x4*)(reg + ((d * 256 + qf * 64 + g * 16) ^ ((d & 7) << 4))) = o[qf][df];
      }
      if (l15 == 0) {
        *(f32x4*)&mlA[(s * 4 + qf) * 16 + g * 4] = me[qf];
        *(f32x4*)&mlB[(s * 4 + qf) * 16 + g * 4] = le[qf];
      }
    }
  };
  auto merge = [&](char* reg, int s) {
#pragma unroll
    for (int qf = 0; qf < 4; ++qf) {
      f32x4 mp = *(f32x4*)&mlA[(s * 4 + qf) * 16 + g * 4];
      f32x4 lp = *(f32x4*)&mlB[(s * 4 + qf) * 16 + g * 4];
      f32x4 op[4];
#pragma unroll
      for (int df = 0; df < 4; ++df) {
        int d = df * 16 + l15;
        op[df] = *(f32x4*)(reg + ((d * 256 + qf * 64 + g * 16) ^ ((d & 7) << 4)));
      }
#pragma unroll
      for (int e = 0; e < 4; ++e) {
        float mf = fmaxf(me[qf][e], mp[e]);
        float as = exp2f(me[qf][e] - mf), ap = exp2f(mp[e] - mf);
        le[qf][e] = le[qf][e] * as + lp[e] * ap;
        me[qf][e] = mf;
#pragma unroll
        for (int df = 0; df < 4; ++df)
          o[qf][df][e] = o[qf][df][e] * as + op[df][e] * ap;
      }
    }
  };

  __syncthreads();  // done with Ps
  if (w == 1) publish(smem, 1);
  if (w == 3) publish(smem + 16384, 3);
  __syncthreads();
  if (w == 0) merge(smem, 1);
  if (w == 2) merge(smem + 16384, 3);
  __syncthreads();
  if (w == 2) publish(smem, 2);
  __syncthreads();
  if (w == 0) {
    merge(smem, 2);
    int n = nh >> 2, head = nh & 3;
#pragma unroll
    for (int qf = 0; qf < 4; ++qf) {
      f32x4 rinv;
#pragma unroll
      for (int e = 0; e < 4; ++e) rinv[e] = 1.f / le[qf][e];
#pragma unroll
      for (int df = 0; df < 4; ++df) {
        int d = df * 16 + l15;
#pragma unroll
        for (int e = 0; e < 4; ++e) {
          int qn = q0 + qf * 16 + g * 4 + e;
          size_t off = (((size_t)n * HW) + head * 1024 + (qn >> 2)) * CCH + (qn & 3) * DH + d;
          O[off] = f2bf(o[qf][df][e] * rinv[e]);
        }
      }
    }
  }
}

// ---------------- proj GEMM + bias + transpose to (n, c, hw) fp32 ----------------
__global__ __launch_bounds__(256) void k_proj(
    const u16* __restrict__ A, const u16* __restrict__ W,
    const float* __restrict__ bias, float* __restrict__ out) {
  __shared__ __attribute__((aligned(16))) u16 As[64 * 32];
  __shared__ __attribute__((aligned(16))) u16 Bs[64 * 32];
  int Rb = blockIdx.x * 64, Cb = blockIdx.y * 64;
  int t = threadIdx.x, lane = t & 63, wv = t >> 6;
  int wr = (wv >> 1) * 32, wc = (wv & 1) * 32;
  f32x4 acc[2][2] = {};
  for (int kb = 0; kb < CCH; kb += 32) {
    {
      int r = t >> 2, kc = t & 3;
      uint4 v = *(const uint4*)(A + ((size_t)(Rb + r)) * CCH + kb + kc * 8);
      *(uint4*)((char*)As + r * 64 + ((kc * 16) ^ ((r & 3) << 4))) = v;
    }
    {
      int k = t >> 3, jc = (t & 7) * 8;
      union { u16 u[8]; uint4 v; } tmp;
      tmp.v = *(const uint4*)(W + ((size_t)(kb + k)) * CCH + Cb + jc);
#pragma unroll
      for (int i2 = 0; i2 < 8; ++i2) {
        int j = jc + i2;
        *(u16*)((char*)Bs + j * 64 + ((k * 2) ^ ((j & 3) << 4))) = tmp.u[i2];
      }
    }
    __syncthreads();
    bf16x8 af[2], bfr[2];
#pragma unroll
    for (int f = 0; f < 2; ++f) {
      int row = wr + f * 16 + (lane & 15);
      af[f] = *(const bf16x8*)((const char*)As + row * 64 +
                               (((lane >> 4) * 16) ^ ((row & 3) << 4)));
      int col = wc + f * 16 + (lane & 15);
      bfr[f] = *(const bf16x8*)((const char*)Bs + col * 64 +
                                (((lane >> 4) * 16) ^ ((col & 3) << 4)));
    }
#pragma unroll
    for (int i2 = 0; i2 < 2; ++i2)
#pragma unroll
      for (int j2 = 0; j2 < 2; ++j2)
        acc[i2][j2] = __builtin_amdgcn_mfma_f32_16x16x32_bf16(af[i2], bfr[j2], acc[i2][j2], 0, 0, 0);
    __syncthreads();
  }
#pragma unroll
  for (int i2 = 0; i2 < 2; ++i2)
#pragma unroll
    for (int j2 = 0; j2 < 2; ++j2)
#pragma unroll
      for (int e = 0; e < 4; ++e) {
        int R = Rb + wr + i2 * 16 + (lane >> 4) * 4 + e;
        int cg = Cb + wc + j2 * 16 + (lane & 15);
        out[((size_t)((R >> 12) * CCH + cg)) * HW + (R & (HW - 1))] =
            acc[i2][j2][e] + bias[cg];
      }
}

extern "C" void kernel_launch(void* const* d_in, const int* in_sizes, int n_in,
                              void* d_out, int out_size, void* d_ws, size_t ws_size,
                              hipStream_t stream) {
  (void)in_sizes; (void)n_in; (void)out_size; (void)ws_size;
  const float* x      = (const float*)d_in[0];
  const float* gamma  = (const float*)d_in[1];
  const float* beta   = (const float*)d_in[2];
  const float* qkv_w  = (const float*)d_in[3];
  const float* proj_w = (const float*)d_in[4];
  const float* proj_b = (const float*)d_in[5];

  char* ws = (char*)d_ws;
  size_t off = 0;
  float* ab = (float*)(ws + off); off += 4096;
  u16* seq  = (u16*)(ws + off);  off += (size_t)NB * HW * CCH * 2;       // 8 MB
  u16* qwb  = (u16*)(ws + off);  off += (size_t)CCH * 3 * CCH * 2;      // 384 KB
  u16* pwb  = (u16*)(ws + off);  off += (size_t)CCH * CCH * 2;          // 128 KB
  u16* Qb   = (u16*)(ws + off);  off += (size_t)NB * HEADS * SLEN * DH * 2;  // 8 MB
  u16* Kb   = (u16*)(ws + off);  off += (size_t)NB * HEADS * SLEN * DH * 2;
  u16* Vtb  = (u16*)(ws + off);  off += (size_t)NB * HEADS * SLEN * DH * 2;
  u16* oseq = (u16*)(ws + off);  off += (size_t)NB * HW * CCH * 2;

  k_pre<<<384, 256, 0, stream>>>(x, gamma, beta, qkv_w, proj_w, ab, qwb, pwb);
  k_seq<<<dim3(HW / 64, CCH / 64, NB), 256, 0, stream>>>(x, ab, seq);
  k_qkv<<<dim3((NB * HW) / 64, 768 / 64), 256, 0, stream>>>(seq, qwb, Qb, Kb, Vtb);
  k_attn<<<1024, 256, 0, stream>>>(Qb, Kb, Vtb, oseq);
  k_proj<<<dim3((NB * HW) / 64, CCH / 64), 256, 0, stream>>>(oseq, pwb, proj_b, (float*)d_out);
}

// Round 10
// 369.824 us; speedup vs baseline: 1.1776x; 1.1776x over previous
//
#include <hip/hip_runtime.h>
#include <stdint.h>

#define NB 4
#define CCH 256
#define HW 4096
#define HEADS 4
#define DH 64
#define SLEN 4096
#define EPSV 1e-5f
#define NEG_INF (-__builtin_inff())
#define QSCALE (0.125f * 1.44269504088896340736f)

typedef unsigned short u16;
typedef __bf16 bf16x8 __attribute__((ext_vector_type(8)));
typedef float f32x4 __attribute__((ext_vector_type(4)));

__device__ __forceinline__ u16 f2bf(float f) {
  union { float f; uint32_t u; } v; v.f = f;
  uint32_t r = v.u + 0x7FFFu + ((v.u >> 16) & 1u);
  return (u16)(r >> 16);
}

// ---------------- fused BN stats (blocks 0..255) + weight cvt (blocks 256..383) ----
__global__ __launch_bounds__(256) void k_pre(
    const float* __restrict__ x, const float* __restrict__ gamma,
    const float* __restrict__ beta, const float* __restrict__ qw,
    const float* __restrict__ pw, float* __restrict__ ab,
    u16* __restrict__ qwb, u16* __restrict__ pwb) {
  int t = threadIdx.x;
  if (blockIdx.x < 256) {
    int ch = blockIdx.x;
    float s = 0.f, ss = 0.f;
    for (int n = 0; n < NB; ++n) {
      const float4* p = (const float4*)(x + ((size_t)(n * CCH + ch)) * HW);
      for (int i = t; i < HW / 4; i += 256) {
        float4 v = p[i];
        s += v.x + v.y + v.z + v.w;
        ss += v.x * v.x + v.y * v.y + v.z * v.z + v.w * v.w;
      }
    }
#pragma unroll
    for (int mm = 32; mm >= 1; mm >>= 1) {
      s += __shfl_down(s, mm);
      ss += __shfl_down(ss, mm);
    }
    __shared__ float ls[4], lss[4];
    if ((t & 63) == 0) { ls[t >> 6] = s; lss[t >> 6] = ss; }
    __syncthreads();
    if (t == 0) {
      float S = 0.f, SS = 0.f;
      for (int i = 0; i < 4; ++i) { S += ls[i]; SS += lss[i]; }
      float inv = 1.0f / (float)(NB * HW);
      float mean = S * inv;
      float var = SS * inv - mean * mean;
      float a = gamma[ch] * rsqrtf(var + EPSV);
      ab[ch] = a;
      ab[CCH + ch] = beta[ch] - mean * a;
    }
  } else {
    const int NQ = CCH * 3 * CCH;  // 196608
    int i = ((blockIdx.x - 256) * 256 + t) * 8;
    const float* src = (i < NQ) ? (qw + i) : (pw + (i - NQ));
    u16* dst = (i < NQ) ? (qwb + i) : (pwb + (i - NQ));
    float4 v0 = *(const float4*)src;
    float4 v1 = *(const float4*)(src + 4);
    union { u16 u[8]; uint4 v; } o;
    o.u[0] = f2bf(v0.x); o.u[1] = f2bf(v0.y); o.u[2] = f2bf(v0.z); o.u[3] = f2bf(v0.w);
    o.u[4] = f2bf(v1.x); o.u[5] = f2bf(v1.y); o.u[6] = f2bf(v1.z); o.u[7] = f2bf(v1.w);
    *(uint4*)dst = o.v;
  }
}

// ---------------- normalize + transpose -> seq bf16 (n, hw, c) ----------------
__global__ __launch_bounds__(256) void k_seq(
    const float* __restrict__ x, const float* __restrict__ ab,
    u16* __restrict__ seq) {
  __shared__ float tile[64][65];
  int pb = blockIdx.x * 64, cb = blockIdx.y * 64, n = blockIdx.z;
  int t = threadIdx.x;
  {
    int cl = t >> 2, pc = (t & 3) * 16;
    float a = ab[cb + cl], b = ab[CCH + cb + cl];
    const float* src = x + ((size_t)(n * CCH + cb + cl)) * HW + pb + pc;
#pragma unroll
    for (int i = 0; i < 4; ++i) {
      float4 v = *(const float4*)(src + i * 4);
      tile[cl][pc + i * 4 + 0] = v.x * a + b;
      tile[cl][pc + i * 4 + 1] = v.y * a + b;
      tile[cl][pc + i * 4 + 2] = v.z * a + b;
      tile[cl][pc + i * 4 + 3] = v.w * a + b;
    }
  }
  __syncthreads();
  {
    int pl = t >> 2, cs = (t & 3) * 16;
    union { u16 u[16]; uint4 v[2]; } tmp;
#pragma unroll
    for (int i = 0; i < 16; ++i) tmp.u[i] = f2bf(tile[cs + i][pl]);
    u16* dst = seq + ((size_t)(n * HW + pb + pl)) * CCH + cb + cs;
    *(uint4*)dst = tmp.v[0];
    *(uint4*)(dst + 8) = tmp.v[1];
  }
}

// ---------------- QKV GEMM -> scatter Q(scaled)/K/Vt ----------------
__global__ __launch_bounds__(256) void k_qkv(
    const u16* __restrict__ seq, const u16* __restrict__ w,
    u16* __restrict__ Q, u16* __restrict__ K, u16* __restrict__ Vt) {
  __shared__ __attribute__((aligned(16))) u16 As[64 * 32];
  __shared__ __attribute__((aligned(16))) u16 Bs[64 * 32];
  int Rb = blockIdx.x * 64, Cb = blockIdx.y * 64;
  int t = threadIdx.x, lane = t & 63, wv = t >> 6;
  int wr = (wv >> 1) * 32, wc = (wv & 1) * 32;
  f32x4 acc[2][2] = {};
  for (int kb = 0; kb < CCH; kb += 32) {
    {
      int r = t >> 2, kc = t & 3;
      uint4 v = *(const uint4*)(seq + ((size_t)(Rb + r)) * CCH + kb + kc * 8);
      *(uint4*)((char*)As + r * 64 + ((kc * 16) ^ ((r & 3) << 4))) = v;
    }
    {
      int k = t >> 3, jc = (t & 7) * 8;
      union { u16 u[8]; uint4 v; } tmp;
      tmp.v = *(const uint4*)(w + ((size_t)(kb + k)) * 768 + Cb + jc);
#pragma unroll
      for (int i2 = 0; i2 < 8; ++i2) {
        int j = jc + i2;
        *(u16*)((char*)Bs + j * 64 + ((k * 2) ^ ((j & 3) << 4))) = tmp.u[i2];
      }
    }
    __syncthreads();
    bf16x8 af[2], bfr[2];
#pragma unroll
    for (int f = 0; f < 2; ++f) {
      int row = wr + f * 16 + (lane & 15);
      af[f] = *(const bf16x8*)((const char*)As + row * 64 +
                               (((lane >> 4) * 16) ^ ((row & 3) << 4)));
      int col = wc + f * 16 + (lane & 15);
      bfr[f] = *(const bf16x8*)((const char*)Bs + col * 64 +
                                (((lane >> 4) * 16) ^ ((col & 3) << 4)));
    }
#pragma unroll
    for (int i2 = 0; i2 < 2; ++i2)
#pragma unroll
      for (int j2 = 0; j2 < 2; ++j2)
        acc[i2][j2] = __builtin_amdgcn_mfma_f32_16x16x32_bf16(af[i2], bfr[j2], acc[i2][j2], 0, 0, 0);
    __syncthreads();
  }
#pragma unroll
  for (int i2 = 0; i2 < 2; ++i2)
#pragma unroll
    for (int j2 = 0; j2 < 2; ++j2)
#pragma unroll
      for (int e = 0; e < 4; ++e) {
        int R = Rb + wr + i2 * 16 + (lane >> 4) * 4 + e;
        int cg = Cb + wc + j2 * 16 + (lane & 15);
        int p = R & (HW - 1);
        int head = p >> 10, mq = p & 1023;
        int qn = mq * 4 + cg / 192, tt = cg % 192;
        int nhx = (R >> 12) * HEADS + head;
        float a = acc[i2][j2][e];
        if (tt < 64)
          Q[((size_t)nhx * SLEN + qn) * DH + tt] = f2bf(a * QSCALE);
        else if (tt < 128)
          K[((size_t)nhx * SLEN + qn) * DH + tt - 64] = f2bf(a);
        else
          Vt[(size_t)nhx * SLEN * DH + (size_t)(tt - 128) * SLEN + qn] = f2bf(a);
      }
}

// ---------------- flash attention: 4 waves = qsplit2 x kvsplit2 ----------------
// Per-wave state halved vs the 64q version: o[2][4] (32 regs) + qv[2][2] (16)
// -> target 3 waves/SIMD (launch_bounds(256,3)). R3-style loop: load K,V at
// tile top, no manual pipelining (R5/R6 showed any 2-deep reg scheme spills).
// Gate-first softmax (no cross-lane in common path) + XCD-chunked swizzle.
__global__ __launch_bounds__(256, 3) void k_attn(
    const u16* __restrict__ Q, const u16* __restrict__ K,
    const u16* __restrict__ Vt, u16* __restrict__ O) {
  __shared__ __attribute__((aligned(16))) char smem[16384 + 1024];
  float* mlA = (float*)(smem + 16384);        // [8][16] (w*2+qf) x row
  float* mlB = (float*)(smem + 16384 + 512);
  // XCD-chunked swizzle: each XCD gets a contiguous 128-block chunk
  // (= 2 heads' K/V -> fits its 4MB L2). Verified: FETCH 70->20 MB.
  int bid = blockIdx.x;
  int wid = (bid & 7) * 128 + (bid >> 3);
  int nh = wid >> 6;
  int q0 = (wid & 63) * 64;
  int t = threadIdx.x, lane = t & 63, w = t >> 6;
  int qhalf = w & 1, kvslot = w >> 1;
  int l15 = lane & 15, g = lane >> 4;
  size_t base = (size_t)nh * SLEN * DH;
  char* Ps = smem + w * 4096;  // [32 q][64 kv] bf16, swizzled
  int swz = (l15 & 7) << 4;

  // Q fragments (B-operand: col = q = l15, k = d); this wave's 32 q rows
  bf16x8 qv[2][2];
#pragma unroll
  for (int qf = 0; qf < 2; ++qf) {
    const u16* qp = Q + base + (size_t)(q0 + qhalf * 32 + qf * 16 + l15) * DH + g * 8;
    qv[qf][0] = *(const bf16x8*)qp;
    qv[qf][1] = *(const bf16x8*)(qp + 32);
  }

  f32x4 o[2][4] = {};
  float m[2] = {NEG_INF, NEG_INF};
  float lsum[2] = {0.f, 0.f};

  const u16* Kptr = K + base + (size_t)l15 * DH + g * 8;
  const u16* Vptr = Vt + base + (size_t)l15 * SLEN + g * 8;

  bf16x8 kf[4][2], vf[4][2];

  const int TILES = SLEN / 64 / 2;  // 32 per wave
  int kvBase = kvslot * (SLEN / 2);
  for (int tt = 0; tt < TILES; ++tt) {
    int kv0 = kvBase + tt * 64;
    // K fragments (A-operand: row = kv = cf*16 + l15, k = d)
#pragma unroll
    for (int cf = 0; cf < 4; ++cf) {
      const u16* kp = Kptr + (size_t)(kv0 + cf * 16) * DH;
      kf[cf][0] = *(const bf16x8*)kp;
      kf[cf][1] = *(const bf16x8*)(kp + 32);
    }
    // V^T fragments (B-operand for PV: col = d = df*16 + l15, k = kv)
#pragma unroll
    for (int df = 0; df < 4; ++df) {
      const u16* vp = Vptr + (size_t)(df * 16) * SLEN + kv0;
      vf[df][0] = *(const bf16x8*)vp;
      vf[df][1] = *(const bf16x8*)(vp + 32);
    }
#pragma unroll
    for (int qf = 0; qf < 2; ++qf) {
      f32x4 st[4];
      __builtin_amdgcn_s_setprio(1);
#pragma unroll
      for (int cf = 0; cf < 4; ++cf) {
        f32x4 a = {};
        a = __builtin_amdgcn_mfma_f32_16x16x32_bf16(kf[cf][0], qv[qf][0], a, 0, 0, 0);
        a = __builtin_amdgcn_mfma_f32_16x16x32_bf16(kf[cf][1], qv[qf][1], a, 0, 0, 0);
        st[cf] = a;
      }
      __builtin_amdgcn_s_setprio(0);
      // in-lane max tree, gate BEFORE any exp/cross-lane work
      float mx0 = fmaxf(fmaxf(st[0][0], st[0][1]), fmaxf(st[0][2], st[0][3]));
      float mx1 = fmaxf(fmaxf(st[1][0], st[1][1]), fmaxf(st[1][2], st[1][3]));
      float mx2 = fmaxf(fmaxf(st[2][0], st[2][1]), fmaxf(st[2][2], st[2][3]));
      float mx3 = fmaxf(fmaxf(st[3][0], st[3][1]), fmaxf(st[3][2], st[3][3]));
      float stmax = fmaxf(fmaxf(mx0, mx1), fmaxf(mx2, mx3));
      if (__any(stmax > m[qf] + 8.0f)) {
        float mx = fmaxf(stmax, __shfl_xor(stmax, 16));
        mx = fmaxf(mx, __shfl_xor(mx, 32));
        float mn = fmaxf(m[qf], mx);
        float al = exp2f(m[qf] - mn);
        m[qf] = mn;
        lsum[qf] *= al;
#pragma unroll
        for (int e = 0; e < 4; ++e) {
          float ae = __shfl(al, (lane & 48) | (((lane >> 4) << 2) + e));
#pragma unroll
          for (int df = 0; df < 4; ++df) o[qf][df][e] *= ae;
        }
      }
      float mq = m[qf];
      f32x4 lsv = {0.f, 0.f, 0.f, 0.f};
#pragma unroll
      for (int cf = 0; cf < 4; ++cf) {
        union { __bf16 h[4]; uint2 v; } pk;
#pragma unroll
        for (int e = 0; e < 4; ++e) {
          float p = exp2f(st[cf][e] - mq);
          lsv[e] += p;
          pk.h[e] = (__bf16)p;
        }
        *(uint2*)(Ps + (qf * 16 + l15) * 128 + ((cf * 32 + g * 8) ^ swz)) = pk.v;
      }
      lsum[qf] += lsv[0] + lsv[1] + lsv[2] + lsv[3];
    }
    // PV
#pragma unroll
    for (int qf = 0; qf < 2; ++qf) {
#pragma unroll
      for (int ks = 0; ks < 2; ++ks) {
        bf16x8 pa = *(const bf16x8*)(Ps + (qf * 16 + l15) * 128 + ((ks * 64 + g * 16) ^ swz));
        __builtin_amdgcn_s_setprio(1);
#pragma unroll
        for (int df = 0; df < 4; ++df)
          o[qf][df] = __builtin_amdgcn_mfma_f32_16x16x32_bf16(pa, vf[df][ks], o[qf][df], 0, 0, 0);
        __builtin_amdgcn_s_setprio(0);
      }
    }
  }

  // finalize: reduce l across g, convert m/l to C-frag layout
#pragma unroll
  for (int qf = 0; qf < 2; ++qf) {
    lsum[qf] += __shfl_xor(lsum[qf], 16);
    lsum[qf] += __shfl_xor(lsum[qf], 32);
  }
  f32x4 me[2], le[2];
#pragma unroll
  for (int qf = 0; qf < 2; ++qf)
#pragma unroll
    for (int e = 0; e < 4; ++e) {
      int idx = (lane & 48) | (((lane >> 4) & 3) << 2) | e;
      me[qf][e] = __shfl(m[qf], idx);
      le[qf][e] = __shfl(lsum[qf], idx);
    }

  __syncthreads();  // everyone done with Ps
  if (kvslot == 1) {
    // publish O tile + m/l to this qhalf's region
    char* reg = smem + qhalf * 8192;
#pragma unroll
    for (int qf = 0; qf < 2; ++qf) {
#pragma unroll
      for (int df = 0; df < 4; ++df) {
        int d = df * 16 + l15;
        *(f32x4*)(reg + ((d * 128 + qf * 64 + g * 16) ^ ((d & 7) << 4))) = o[qf][df];
      }
      if (l15 == 0) {
        *(f32x4*)&mlA[(w * 2 + qf) * 16 + g * 4] = me[qf];
        *(f32x4*)&mlB[(w * 2 + qf) * 16 + g * 4] = le[qf];
      }
    }
  }
  __syncthreads();
  if (kvslot == 0) {
    char* reg = smem + qhalf * 8192;
    int sw = w + 2;  // partner wave (same qhalf, kvslot 1)
    int n = nh >> 2, head = nh & 3;
#pragma unroll
    for (int qf = 0; qf < 2; ++qf) {
      f32x4 mp = *(f32x4*)&mlA[(sw * 2 + qf) * 16 + g * 4];
      f32x4 lp = *(f32x4*)&mlB[(sw * 2 + qf) * 16 + g * 4];
      f32x4 op[4];
#pragma unroll
      for (int df = 0; df < 4; ++df) {
        int d = df * 16 + l15;
        op[df] = *(f32x4*)(reg + ((d * 128 + qf * 64 + g * 16) ^ ((d & 7) << 4)));
      }
      f32x4 rinv;
#pragma unroll
      for (int e = 0; e < 4; ++e) {
        float mf = fmaxf(me[qf][e], mp[e]);
        float as = exp2f(me[qf][e] - mf), ap = exp2f(mp[e] - mf);
        float lf = le[qf][e] * as + lp[e] * ap;
        rinv[e] = 1.f / lf;
#pragma unroll
        for (int df = 0; df < 4; ++df)
          o[qf][df][e] = (o[qf][df][e] * as + op[df][e] * ap);
      }
#pragma unroll
      for (int df = 0; df < 4; ++df) {
        int d = df * 16 + l15;
#pragma unroll
        for (int e = 0; e < 4; ++e) {
          int qn = q0 + qhalf * 32 + qf * 16 + g * 4 + e;
          size_t off = (((size_t)n * HW) + head * 1024 + (qn >> 2)) * CCH + (qn & 3) * DH + d;
          O[off] = f2bf(o[qf][df][e] * rinv[e]);
        }
      }
    }
  }
}

// ---------------- proj GEMM + bias + transpose to (n, c, hw) fp32 ----------------
__global__ __launch_bounds__(256) void k_proj(
    const u16* __restrict__ A, const u16* __restrict__ W,
    const float* __restrict__ bias, float* __restrict__ out) {
  __shared__ __attribute__((aligned(16))) u16 As[64 * 32];
  __shared__ __attribute__((aligned(16))) u16 Bs[64 * 32];
  int Rb = blockIdx.x * 64, Cb = blockIdx.y * 64;
  int t = threadIdx.x, lane = t & 63, wv = t >> 6;
  int wr = (wv >> 1) * 32, wc = (wv & 1) * 32;
  f32x4 acc[2][2] = {};
  for (int kb = 0; kb < CCH; kb += 32) {
    {
      int r = t >> 2, kc = t & 3;
      uint4 v = *(const uint4*)(A + ((size_t)(Rb + r)) * CCH + kb + kc * 8);
      *(uint4*)((char*)As + r * 64 + ((kc * 16) ^ ((r & 3) << 4))) = v;
    }
    {
      int k = t >> 3, jc = (t & 7) * 8;
      union { u16 u[8]; uint4 v; } tmp;
      tmp.v = *(const uint4*)(W + ((size_t)(kb + k)) * CCH + Cb + jc);
#pragma unroll
      for (int i2 = 0; i2 < 8; ++i2) {
        int j = jc + i2;
        *(u16*)((char*)Bs + j * 64 + ((k * 2) ^ ((j & 3) << 4))) = tmp.u[i2];
      }
    }
    __syncthreads();
    bf16x8 af[2], bfr[2];
#pragma unroll
    for (int f = 0; f < 2; ++f) {
      int row = wr + f * 16 + (lane & 15);
      af[f] = *(const bf16x8*)((const char*)As + row * 64 +
                               (((lane >> 4) * 16) ^ ((row & 3) << 4)));
      int col = wc + f * 16 + (lane & 15);
      bfr[f] = *(const bf16x8*)((const char*)Bs + col * 64 +
                                (((lane >> 4) * 16) ^ ((col & 3) << 4)));
    }
#pragma unroll
    for (int i2 = 0; i2 < 2; ++i2)
#pragma unroll
      for (int j2 = 0; j2 < 2; ++j2)
        acc[i2][j2] = __builtin_amdgcn_mfma_f32_16x16x32_bf16(af[i2], bfr[j2], acc[i2][j2], 0, 0, 0);
    __syncthreads();
  }
#pragma unroll
  for (int i2 = 0; i2 < 2; ++i2)
#pragma unroll
    for (int j2 = 0; j2 < 2; ++j2)
#pragma unroll
      for (int e = 0; e < 4; ++e) {
        int R = Rb + wr + i2 * 16 + (lane >> 4) * 4 + e;
        int cg = Cb + wc + j2 * 16 + (lane & 15);
        out[((size_t)((R >> 12) * CCH + cg)) * HW + (R & (HW - 1))] =
            acc[i2][j2][e] + bias[cg];
      }
}

extern "C" void kernel_launch(void* const* d_in, const int* in_sizes, int n_in,
                              void* d_out, int out_size, void* d_ws, size_t ws_size,
                              hipStream_t stream) {
  (void)in_sizes; (void)n_in; (void)out_size; (void)ws_size;
  const float* x      = (const float*)d_in[0];
  const float* gamma  = (const float*)d_in[1];
  const float* beta   = (const float*)d_in[2];
  const float* qkv_w  = (const float*)d_in[3];
  const float* proj_w = (const float*)d_in[4];
  const float* proj_b = (const float*)d_in[5];

  char* ws = (char*)d_ws;
  size_t off = 0;
  float* ab = (float*)(ws + off); off += 4096;
  u16* seq  = (u16*)(ws + off);  off += (size_t)NB * HW * CCH * 2;       // 8 MB
  u16* qwb  = (u16*)(ws + off);  off += (size_t)CCH * 3 * CCH * 2;      // 384 KB
  u16* pwb  = (u16*)(ws + off);  off += (size_t)CCH * CCH * 2;          // 128 KB
  u16* Qb   = (u16*)(ws + off);  off += (size_t)NB * HEADS * SLEN * DH * 2;  // 8 MB
  u16* Kb   = (u16*)(ws + off);  off += (size_t)NB * HEADS * SLEN * DH * 2;
  u16* Vtb  = (u16*)(ws + off);  off += (size_t)NB * HEADS * SLEN * DH * 2;
  u16* oseq = (u16*)(ws + off);  off += (size_t)NB * HW * CCH * 2;

  k_pre<<<384, 256, 0, stream>>>(x, gamma, beta, qkv_w, proj_w, ab, qwb, pwb);
  k_seq<<<dim3(HW / 64, CCH / 64, NB), 256, 0, stream>>>(x, ab, seq);
  k_qkv<<<dim3((NB * HW) / 64, 768 / 64), 256, 0, stream>>>(seq, qwb, Qb, Kb, Vtb);
  k_attn<<<1024, 256, 0, stream>>>(Qb, Kb, Vtb, oseq);
  k_proj<<<dim3((NB * HW) / 64, CCH / 64), 256, 0, stream>>>(oseq, pwb, proj_b, (float*)d_out);
}

// Round 11
// 337.946 us; speedup vs baseline: 1.2886x; 1.0943x over previous
//
#include <hip/hip_runtime.h>
#include <stdint.h>

#define NB 4
#define CCH 256
#define HW 4096
#define HEADS 4
#define DH 64
#define SLEN 4096
#define EPSV 1e-5f
#define NEG_INF (-__builtin_inff())
#define QSCALE (0.125f * 1.44269504088896340736f)

typedef unsigned short u16;
typedef __bf16 bf16x8 __attribute__((ext_vector_type(8)));
typedef float f32x4 __attribute__((ext_vector_type(4)));

__device__ __forceinline__ u16 f2bf(float f) {
  union { float f; uint32_t u; } v; v.f = f;
  uint32_t r = v.u + 0x7FFFu + ((v.u >> 16) & 1u);
  return (u16)(r >> 16);
}

// ---------------- fused BN stats (blocks 0..255) + weight cvt (blocks 256..383) ----
__global__ __launch_bounds__(256) void k_pre(
    const float* __restrict__ x, const float* __restrict__ gamma,
    const float* __restrict__ beta, const float* __restrict__ qw,
    const float* __restrict__ pw, float* __restrict__ ab,
    u16* __restrict__ qwb, u16* __restrict__ pwb) {
  int t = threadIdx.x;
  if (blockIdx.x < 256) {
    int ch = blockIdx.x;
    float s = 0.f, ss = 0.f;
    for (int n = 0; n < NB; ++n) {
      const float4* p = (const float4*)(x + ((size_t)(n * CCH + ch)) * HW);
      for (int i = t; i < HW / 4; i += 256) {
        float4 v = p[i];
        s += v.x + v.y + v.z + v.w;
        ss += v.x * v.x + v.y * v.y + v.z * v.z + v.w * v.w;
      }
    }
#pragma unroll
    for (int mm = 32; mm >= 1; mm >>= 1) {
      s += __shfl_down(s, mm);
      ss += __shfl_down(ss, mm);
    }
    __shared__ float ls[4], lss[4];
    if ((t & 63) == 0) { ls[t >> 6] = s; lss[t >> 6] = ss; }
    __syncthreads();
    if (t == 0) {
      float S = 0.f, SS = 0.f;
      for (int i = 0; i < 4; ++i) { S += ls[i]; SS += lss[i]; }
      float inv = 1.0f / (float)(NB * HW);
      float mean = S * inv;
      float var = SS * inv - mean * mean;
      float a = gamma[ch] * rsqrtf(var + EPSV);
      ab[ch] = a;
      ab[CCH + ch] = beta[ch] - mean * a;
    }
  } else {
    const int NQ = CCH * 3 * CCH;  // 196608
    int i = ((blockIdx.x - 256) * 256 + t) * 8;
    const float* src = (i < NQ) ? (qw + i) : (pw + (i - NQ));
    u16* dst = (i < NQ) ? (qwb + i) : (pwb + (i - NQ));
    float4 v0 = *(const float4*)src;
    float4 v1 = *(const float4*)(src + 4);
    union { u16 u[8]; uint4 v; } o;
    o.u[0] = f2bf(v0.x); o.u[1] = f2bf(v0.y); o.u[2] = f2bf(v0.z); o.u[3] = f2bf(v0.w);
    o.u[4] = f2bf(v1.x); o.u[5] = f2bf(v1.y); o.u[6] = f2bf(v1.z); o.u[7] = f2bf(v1.w);
    *(uint4*)dst = o.v;
  }
}

// ---------------- normalize + transpose -> seq bf16 (n, hw, c) ----------------
__global__ __launch_bounds__(256) void k_seq(
    const float* __restrict__ x, const float* __restrict__ ab,
    u16* __restrict__ seq) {
  __shared__ float tile[64][65];
  int pb = blockIdx.x * 64, cb = blockIdx.y * 64, n = blockIdx.z;
  int t = threadIdx.x;
  {
    int cl = t >> 2, pc = (t & 3) * 16;
    float a = ab[cb + cl], b = ab[CCH + cb + cl];
    const float* src = x + ((size_t)(n * CCH + cb + cl)) * HW + pb + pc;
#pragma unroll
    for (int i = 0; i < 4; ++i) {
      float4 v = *(const float4*)(src + i * 4);
      tile[cl][pc + i * 4 + 0] = v.x * a + b;
      tile[cl][pc + i * 4 + 1] = v.y * a + b;
      tile[cl][pc + i * 4 + 2] = v.z * a + b;
      tile[cl][pc + i * 4 + 3] = v.w * a + b;
    }
  }
  __syncthreads();
  {
    int pl = t >> 2, cs = (t & 3) * 16;
    union { u16 u[16]; uint4 v[2]; } tmp;
#pragma unroll
    for (int i = 0; i < 16; ++i) tmp.u[i] = f2bf(tile[cs + i][pl]);
    u16* dst = seq + ((size_t)(n * HW + pb + pl)) * CCH + cb + cs;
    *(uint4*)dst = tmp.v[0];
    *(uint4*)(dst + 8) = tmp.v[1];
  }
}

// ---------------- QKV GEMM -> scatter Q(scaled)/K/Vt ----------------
__global__ __launch_bounds__(256) void k_qkv(
    const u16* __restrict__ seq, const u16* __restrict__ w,
    u16* __restrict__ Q, u16* __restrict__ K, u16* __restrict__ Vt) {
  __shared__ __attribute__((aligned(16))) u16 As[64 * 32];
  __shared__ __attribute__((aligned(16))) u16 Bs[64 * 32];
  int Rb = blockIdx.x * 64, Cb = blockIdx.y * 64;
  int t = threadIdx.x, lane = t & 63, wv = t >> 6;
  int wr = (wv >> 1) * 32, wc = (wv & 1) * 32;
  f32x4 acc[2][2] = {};
  for (int kb = 0; kb < CCH; kb += 32) {
    {
      int r = t >> 2, kc = t & 3;
      uint4 v = *(const uint4*)(seq + ((size_t)(Rb + r)) * CCH + kb + kc * 8);
      *(uint4*)((char*)As + r * 64 + ((kc * 16) ^ ((r & 3) << 4))) = v;
    }
    {
      int k = t >> 3, jc = (t & 7) * 8;
      union { u16 u[8]; uint4 v; } tmp;
      tmp.v = *(const uint4*)(w + ((size_t)(kb + k)) * 768 + Cb + jc);
#pragma unroll
      for (int i2 = 0; i2 < 8; ++i2) {
        int j = jc + i2;
        *(u16*)((char*)Bs + j * 64 + ((k * 2) ^ ((j & 3) << 4))) = tmp.u[i2];
      }
    }
    __syncthreads();
    bf16x8 af[2], bfr[2];
#pragma unroll
    for (int f = 0; f < 2; ++f) {
      int row = wr + f * 16 + (lane & 15);
      af[f] = *(const bf16x8*)((const char*)As + row * 64 +
                               (((lane >> 4) * 16) ^ ((row & 3) << 4)));
      int col = wc + f * 16 + (lane & 15);
      bfr[f] = *(const bf16x8*)((const char*)Bs + col * 64 +
                                (((lane >> 4) * 16) ^ ((col & 3) << 4)));
    }
#pragma unroll
    for (int i2 = 0; i2 < 2; ++i2)
#pragma unroll
      for (int j2 = 0; j2 < 2; ++j2)
        acc[i2][j2] = __builtin_amdgcn_mfma_f32_16x16x32_bf16(af[i2], bfr[j2], acc[i2][j2], 0, 0, 0);
    __syncthreads();
  }
#pragma unroll
  for (int i2 = 0; i2 < 2; ++i2)
#pragma unroll
    for (int j2 = 0; j2 < 2; ++j2)
#pragma unroll
      for (int e = 0; e < 4; ++e) {
        int R = Rb + wr + i2 * 16 + (lane >> 4) * 4 + e;
        int cg = Cb + wc + j2 * 16 + (lane & 15);
        int p = R & (HW - 1);
        int head = p >> 10, mq = p & 1023;
        int qn = mq * 4 + cg / 192, tt = cg % 192;
        int nhx = (R >> 12) * HEADS + head;
        float a = acc[i2][j2][e];
        if (tt < 64)
          Q[((size_t)nhx * SLEN + qn) * DH + tt] = f2bf(a * QSCALE);
        else if (tt < 128)
          K[((size_t)nhx * SLEN + qn) * DH + tt - 64] = f2bf(a);
        else
          Vt[(size_t)nhx * SLEN * DH + (size_t)(tt - 128) * SLEN + qn] = f2bf(a);
      }
}

// ---------------- flash attention: 4 waves, 64q shared, kvsplit4 ----------------
// R3 structure (best measured: 164us) with register shaves for 3 waves/SIMD:
//  - Q lives in block-shared LDS (all 4 waves use the same 64 q rows): -32 VGPR
//  - kf and vf in disjoint scopes (V loaded AFTER qksoft): regs shared: -32 VGPR
// Gate-first softmax + XCD-chunked swizzle (both verified).
__global__ __launch_bounds__(256, 3) void k_attn(
    const u16* __restrict__ Q, const u16* __restrict__ K,
    const u16* __restrict__ Vt, u16* __restrict__ O) {
  __shared__ __attribute__((aligned(16))) char smem[32768 + 8192 + 2048];
  char* Qs = smem + 32768;                     // [64 q][128B] swizzled
  float* mlA = (float*)(smem + 40960);         // [slot4][qf4][row16] m
  float* mlB = (float*)(smem + 40960 + 1024);  // [slot4][qf4][row16] l
  int bid = blockIdx.x;
  int wid = (bid & 7) * 128 + (bid >> 3);      // XCD-chunked swizzle
  int nh = wid >> 6;
  int q0 = (wid & 63) * 64;
  int t = threadIdx.x, lane = t & 63, w = t >> 6;
  int l15 = lane & 15, g = lane >> 4;
  size_t base = (size_t)nh * SLEN * DH;
  char* Ps = smem + w * 8192;  // [64 q][64 kv] bf16, swizzled
  int swz = (l15 & 7) << 4;

  // stage Q tile into LDS (coalesced, swizzled rows)
  {
#pragma unroll
    for (int c2 = 0; c2 < 2; ++c2) {
      int c = t * 2 + c2;          // 16B chunk index, 512 total
      int row = c >> 3, col = c & 7;
      uint4 v = *(const uint4*)(Q + base + (size_t)(q0 + row) * DH + col * 8);
      *(uint4*)(Qs + row * 128 + ((col * 16) ^ ((row & 7) << 4))) = v;
    }
  }
  __syncthreads();

  f32x4 o[4][4] = {};
  float m[4] = {NEG_INF, NEG_INF, NEG_INF, NEG_INF};
  float lsum[4] = {0.f, 0.f, 0.f, 0.f};

  const u16* Kptr = K + base + (size_t)l15 * DH + g * 8;
  const u16* Vptr = Vt + base + (size_t)l15 * SLEN + g * 8;

  const int TILES = SLEN / 64 / 4;  // 16 per wave
  int kvBase = w * TILES * 64;
  for (int tt = 0; tt < TILES; ++tt) {
    int kv0 = kvBase + tt * 64;
    {  // ---- QK^T + softmax phase (kf live only here) ----
      bf16x8 kf[4][2];
#pragma unroll
      for (int cf = 0; cf < 4; ++cf) {
        const u16* kp = Kptr + (size_t)(kv0 + cf * 16) * DH;
        kf[cf][0] = *(const bf16x8*)kp;
        kf[cf][1] = *(const bf16x8*)(kp + 32);
      }
#pragma unroll
      for (int qf = 0; qf < 4; ++qf) {
        bf16x8 qv0 = *(const bf16x8*)(Qs + (qf * 16 + l15) * 128 + ((g * 16) ^ swz));
        bf16x8 qv1 = *(const bf16x8*)(Qs + (qf * 16 + l15) * 128 + ((64 + g * 16) ^ swz));
        f32x4 st[4];
        __builtin_amdgcn_s_setprio(1);
#pragma unroll
        for (int cf = 0; cf < 4; ++cf) {
          f32x4 a = {};
          a = __builtin_amdgcn_mfma_f32_16x16x32_bf16(kf[cf][0], qv0, a, 0, 0, 0);
          a = __builtin_amdgcn_mfma_f32_16x16x32_bf16(kf[cf][1], qv1, a, 0, 0, 0);
          st[cf] = a;
        }
        __builtin_amdgcn_s_setprio(0);
        // in-lane max tree, gate BEFORE any exp/cross-lane work
        float mx0 = fmaxf(fmaxf(st[0][0], st[0][1]), fmaxf(st[0][2], st[0][3]));
        float mx1 = fmaxf(fmaxf(st[1][0], st[1][1]), fmaxf(st[1][2], st[1][3]));
        float mx2 = fmaxf(fmaxf(st[2][0], st[2][1]), fmaxf(st[2][2], st[2][3]));
        float mx3 = fmaxf(fmaxf(st[3][0], st[3][1]), fmaxf(st[3][2], st[3][3]));
        float stmax = fmaxf(fmaxf(mx0, mx1), fmaxf(mx2, mx3));
        if (__any(stmax > m[qf] + 8.0f)) {
          float mx = fmaxf(stmax, __shfl_xor(stmax, 16));
          mx = fmaxf(mx, __shfl_xor(mx, 32));
          float mn = fmaxf(m[qf], mx);
          float al = exp2f(m[qf] - mn);
          m[qf] = mn;
          lsum[qf] *= al;
#pragma unroll
          for (int e = 0; e < 4; ++e) {
            float ae = __shfl(al, (lane & 48) | (((lane >> 4) << 2) + e));
#pragma unroll
            for (int df = 0; df < 4; ++df) o[qf][df][e] *= ae;
          }
        }
        float mq = m[qf];
        f32x4 lsv = {0.f, 0.f, 0.f, 0.f};
#pragma unroll
        for (int cf = 0; cf < 4; ++cf) {
          union { __bf16 h[4]; uint2 v; } pk;
#pragma unroll
          for (int e = 0; e < 4; ++e) {
            float p = exp2f(st[cf][e] - mq);
            lsv[e] += p;
            pk.h[e] = (__bf16)p;
          }
          *(uint2*)(Ps + (qf * 16 + l15) * 128 + ((cf * 32 + g * 8) ^ swz)) = pk.v;
        }
        lsum[qf] += lsv[0] + lsv[1] + lsv[2] + lsv[3];
      }
    }
    {  // ---- PV phase (vf live only here; reuses kf's registers) ----
      bf16x8 vf[4][2];
#pragma unroll
      for (int df = 0; df < 4; ++df) {
        const u16* vp = Vptr + (size_t)(df * 16) * SLEN + kv0;
        vf[df][0] = *(const bf16x8*)vp;
        vf[df][1] = *(const bf16x8*)(vp + 32);
      }
#pragma unroll
      for (int qf = 0; qf < 4; ++qf) {
#pragma unroll
        for (int ks = 0; ks < 2; ++ks) {
          bf16x8 pa = *(const bf16x8*)(Ps + (qf * 16 + l15) * 128 + ((ks * 64 + g * 16) ^ swz));
          __builtin_amdgcn_s_setprio(1);
#pragma unroll
          for (int df = 0; df < 4; ++df)
            o[qf][df] = __builtin_amdgcn_mfma_f32_16x16x32_bf16(pa, vf[df][ks], o[qf][df], 0, 0, 0);
          __builtin_amdgcn_s_setprio(0);
        }
      }
    }
  }

  // finalize per-wave state: reduce l across g, convert m/l to C-frag layout
#pragma unroll
  for (int qf = 0; qf < 4; ++qf) {
    lsum[qf] += __shfl_xor(lsum[qf], 16);
    lsum[qf] += __shfl_xor(lsum[qf], 32);
  }
  f32x4 me[4], le[4];
#pragma unroll
  for (int qf = 0; qf < 4; ++qf)
#pragma unroll
    for (int e = 0; e < 4; ++e) {
      int idx = (lane & 48) | (((lane >> 4) & 3) << 2) | e;
      me[qf][e] = __shfl(m[qf], idx);
      le[qf][e] = __shfl(lsum[qf], idx);
    }

  auto publish = [&](char* reg, int s) {
#pragma unroll
    for (int qf = 0; qf < 4; ++qf) {
#pragma unroll
      for (int df = 0; df < 4; ++df) {
        int d = df * 16 + l15;
        *(f32x4*)(reg + ((d * 256 + qf * 64 + g * 16) ^ ((d & 7) << 4))) = o[qf][df];
      }
      if (l15 == 0) {
        *(f32x4*)&mlA[(s * 4 + qf) * 16 + g * 4] = me[qf];
        *(f32x4*)&mlB[(s * 4 + qf) * 16 + g * 4] = le[qf];
      }
    }
  };
  auto merge = [&](char* reg, int s) {
#pragma unroll
    for (int qf = 0; qf < 4; ++qf) {
      f32x4 mp = *(f32x4*)&mlA[(s * 4 + qf) * 16 + g * 4];
      f32x4 lp = *(f32x4*)&mlB[(s * 4 + qf) * 16 + g * 4];
      f32x4 op[4];
#pragma unroll
      for (int df = 0; df < 4; ++df) {
        int d = df * 16 + l15;
        op[df] = *(f32x4*)(reg + ((d * 256 + qf * 64 + g * 16) ^ ((d & 7) << 4)));
      }
#pragma unroll
      for (int e = 0; e < 4; ++e) {
        float mf = fmaxf(me[qf][e], mp[e]);
        float as = exp2f(me[qf][e] - mf), ap = exp2f(mp[e] - mf);
        le[qf][e] = le[qf][e] * as + lp[e] * ap;
        me[qf][e] = mf;
#pragma unroll
        for (int df = 0; df < 4; ++df)
          o[qf][df][e] = o[qf][df][e] * as + op[df][e] * ap;
      }
    }
  };

  __syncthreads();  // done with Ps (and Qs)
  if (w == 1) publish(smem, 1);
  if (w == 3) publish(smem + 16384, 3);
  __syncthreads();
  if (w == 0) merge(smem, 1);
  if (w == 2) merge(smem + 16384, 3);
  __syncthreads();
  if (w == 2) publish(smem, 2);
  __syncthreads();
  if (w == 0) {
    merge(smem, 2);
    int n = nh >> 2, head = nh & 3;
#pragma unroll
    for (int qf = 0; qf < 4; ++qf) {
      f32x4 rinv;
#pragma unroll
      for (int e = 0; e < 4; ++e) rinv[e] = 1.f / le[qf][e];
#pragma unroll
      for (int df = 0; df < 4; ++df) {
        int d = df * 16 + l15;
#pragma unroll
        for (int e = 0; e < 4; ++e) {
          int qn = q0 + qf * 16 + g * 4 + e;
          size_t off = (((size_t)n * HW) + head * 1024 + (qn >> 2)) * CCH + (qn & 3) * DH + d;
          O[off] = f2bf(o[qf][df][e] * rinv[e]);
        }
      }
    }
  }
}

// ---------------- proj GEMM + bias + transpose to (n, c, hw) fp32 ----------------
__global__ __launch_bounds__(256) void k_proj(
    const u16* __restrict__ A, const u16* __restrict__ W,
    const float* __restrict__ bias, float* __restrict__ out) {
  __shared__ __attribute__((aligned(16))) u16 As[64 * 32];
  __shared__ __attribute__((aligned(16))) u16 Bs[64 * 32];
  int Rb = blockIdx.x * 64, Cb = blockIdx.y * 64;
  int t = threadIdx.x, lane = t & 63, wv = t >> 6;
  int wr = (wv >> 1) * 32, wc = (wv & 1) * 32;
  f32x4 acc[2][2] = {};
  for (int kb = 0; kb < CCH; kb += 32) {
    {
      int r = t >> 2, kc = t & 3;
      uint4 v = *(const uint4*)(A + ((size_t)(Rb + r)) * CCH + kb + kc * 8);
      *(uint4*)((char*)As + r * 64 + ((kc * 16) ^ ((r & 3) << 4))) = v;
    }
    {
      int k = t >> 3, jc = (t & 7) * 8;
      union { u16 u[8]; uint4 v; } tmp;
      tmp.v = *(const uint4*)(W + ((size_t)(kb + k)) * CCH + Cb + jc);
#pragma unroll
      for (int i2 = 0; i2 < 8; ++i2) {
        int j = jc + i2;
        *(u16*)((char*)Bs + j * 64 + ((k * 2) ^ ((j & 3) << 4))) = tmp.u[i2];
      }
    }
    __syncthreads();
    bf16x8 af[2], bfr[2];
#pragma unroll
    for (int f = 0; f < 2; ++f) {
      int row = wr + f * 16 + (lane & 15);
      af[f] = *(const bf16x8*)((const char*)As + row * 64 +
                               (((lane >> 4) * 16) ^ ((row & 3) << 4)));
      int col = wc + f * 16 + (lane & 15);
      bfr[f] = *(const bf16x8*)((const char*)Bs + col * 64 +
                                (((lane >> 4) * 16) ^ ((col & 3) << 4)));
    }
#pragma unroll
    for (int i2 = 0; i2 < 2; ++i2)
#pragma unroll
      for (int j2 = 0; j2 < 2; ++j2)
        acc[i2][j2] = __builtin_amdgcn_mfma_f32_16x16x32_bf16(af[i2], bfr[j2], acc[i2][j2], 0, 0, 0);
    __syncthreads();
  }
#pragma unroll
  for (int i2 = 0; i2 < 2; ++i2)
#pragma unroll
    for (int j2 = 0; j2 < 2; ++j2)
#pragma unroll
      for (int e = 0; e < 4; ++e) {
        int R = Rb + wr + i2 * 16 + (lane >> 4) * 4 + e;
        int cg = Cb + wc + j2 * 16 + (lane & 15);
        out[((size_t)((R >> 12) * CCH + cg)) * HW + (R & (HW - 1))] =
            acc[i2][j2][e] + bias[cg];
      }
}

extern "C" void kernel_launch(void* const* d_in, const int* in_sizes, int n_in,
                              void* d_out, int out_size, void* d_ws, size_t ws_size,
                              hipStream_t stream) {
  (void)in_sizes; (void)n_in; (void)out_size; (void)ws_size;
  const float* x      = (const float*)d_in[0];
  const float* gamma  = (const float*)d_in[1];
  const float* beta   = (const float*)d_in[2];
  const float* qkv_w  = (const float*)d_in[3];
  const float* proj_w = (const float*)d_in[4];
  const float* proj_b = (const float*)d_in[5];

  char* ws = (char*)d_ws;
  size_t off = 0;
  float* ab = (float*)(ws + off); off += 4096;
  u16* seq  = (u16*)(ws + off);  off += (size_t)NB * HW * CCH * 2;       // 8 MB
  u16* qwb  = (u16*)(ws + off);  off += (size_t)CCH * 3 * CCH * 2;      // 384 KB
  u16* pwb  = (u16*)(ws + off);  off += (size_t)CCH * CCH * 2;          // 128 KB
  u16* Qb   = (u16*)(ws + off);  off += (size_t)NB * HEADS * SLEN * DH * 2;  // 8 MB
  u16* Kb   = (u16*)(ws + off);  off += (size_t)NB * HEADS * SLEN * DH * 2;
  u16* Vtb  = (u16*)(ws + off);  off += (size_t)NB * HEADS * SLEN * DH * 2;
  u16* oseq = (u16*)(ws + off);  off += (size_t)NB * HW * CCH * 2;

  k_pre<<<384, 256, 0, stream>>>(x, gamma, beta, qkv_w, proj_w, ab, qwb, pwb);
  k_seq<<<dim3(HW / 64, CCH / 64, NB), 256, 0, stream>>>(x, ab, seq);
  k_qkv<<<dim3((NB * HW) / 64, 768 / 64), 256, 0, stream>>>(seq, qwb, Qb, Kb, Vtb);
  k_attn<<<1024, 256, 0, stream>>>(Qb, Kb, Vtb, oseq);
  k_proj<<<dim3((NB * HW) / 64, CCH / 64), 256, 0, stream>>>(oseq, pwb, proj_b, (float*)d_out);
}

// Round 14
// 276.296 us; speedup vs baseline: 1.5762x; 1.2231x over previous
//
#include <hip/hip_runtime.h>
#include <stdint.h>

#define NB 4
#define CCH 256
#define HW 4096
#define HEADS 4
#define DH 64
#define SLEN 4096
#define EPSV 1e-5f
#define NEG_INF (-__builtin_inff())
#define QSCALE (0.125f * 1.44269504088896340736f)

typedef unsigned short u16;
typedef __bf16 bf16x8 __attribute__((ext_vector_type(8)));
typedef float f32x4 __attribute__((ext_vector_type(4)));

__device__ __forceinline__ u16 f2bf(float f) {
  union { float f; uint32_t u; } v; v.f = f;
  uint32_t r = v.u + 0x7FFFu + ((v.u >> 16) & 1u);
  return (u16)(r >> 16);
}

// ---------------- fused BN stats (blocks 0..255) + weight cvt (blocks 256..383) ----
__global__ __launch_bounds__(256) void k_pre(
    const float* __restrict__ x, const float* __restrict__ gamma,
    const float* __restrict__ beta, const float* __restrict__ qw,
    const float* __restrict__ pw, float* __restrict__ ab,
    u16* __restrict__ qwb, u16* __restrict__ pwb) {
  int t = threadIdx.x;
  if (blockIdx.x < 256) {
    int ch = blockIdx.x;
    float s = 0.f, ss = 0.f;
    for (int n = 0; n < NB; ++n) {
      const float4* p = (const float4*)(x + ((size_t)(n * CCH + ch)) * HW);
      for (int i = t; i < HW / 4; i += 256) {
        float4 v = p[i];
        s += v.x + v.y + v.z + v.w;
        ss += v.x * v.x + v.y * v.y + v.z * v.z + v.w * v.w;
      }
    }
#pragma unroll
    for (int mm = 32; mm >= 1; mm >>= 1) {
      s += __shfl_down(s, mm);
      ss += __shfl_down(ss, mm);
    }
    __shared__ float ls[4], lss[4];
    if ((t & 63) == 0) { ls[t >> 6] = s; lss[t >> 6] = ss; }
    __syncthreads();
    if (t == 0) {
      float S = 0.f, SS = 0.f;
      for (int i = 0; i < 4; ++i) { S += ls[i]; SS += lss[i]; }
      float inv = 1.0f / (float)(NB * HW);
      float mean = S * inv;
      float var = SS * inv - mean * mean;
      float a = gamma[ch] * rsqrtf(var + EPSV);
      ab[ch] = a;
      ab[CCH + ch] = beta[ch] - mean * a;
    }
  } else {
    const int NQ = CCH * 3 * CCH;  // 196608
    int i = ((blockIdx.x - 256) * 256 + t) * 8;
    const float* src = (i < NQ) ? (qw + i) : (pw + (i - NQ));
    u16* dst = (i < NQ) ? (qwb + i) : (pwb + (i - NQ));
    float4 v0 = *(const float4*)src;
    float4 v1 = *(const float4*)(src + 4);
    union { u16 u[8]; uint4 v; } o;
    o.u[0] = f2bf(v0.x); o.u[1] = f2bf(v0.y); o.u[2] = f2bf(v0.z); o.u[3] = f2bf(v0.w);
    o.u[4] = f2bf(v1.x); o.u[5] = f2bf(v1.y); o.u[6] = f2bf(v1.z); o.u[7] = f2bf(v1.w);
    *(uint4*)dst = o.v;
  }
}

// ---------------- normalize + transpose -> seq bf16 (n, hw, c) ----------------
__global__ __launch_bounds__(256) void k_seq(
    const float* __restrict__ x, const float* __restrict__ ab,
    u16* __restrict__ seq) {
  __shared__ float tile[64][65];
  int pb = blockIdx.x * 64, cb = blockIdx.y * 64, n = blockIdx.z;
  int t = threadIdx.x;
  {
    int cl = t >> 2, pc = (t & 3) * 16;
    float a = ab[cb + cl], b = ab[CCH + cb + cl];
    const float* src = x + ((size_t)(n * CCH + cb + cl)) * HW + pb + pc;
#pragma unroll
    for (int i = 0; i < 4; ++i) {
      float4 v = *(const float4*)(src + i * 4);
      tile[cl][pc + i * 4 + 0] = v.x * a + b;
      tile[cl][pc + i * 4 + 1] = v.y * a + b;
      tile[cl][pc + i * 4 + 2] = v.z * a + b;
      tile[cl][pc + i * 4 + 3] = v.w * a + b;
    }
  }
  __syncthreads();
  {
    int pl = t >> 2, cs = (t & 3) * 16;
    union { u16 u[16]; uint4 v[2]; } tmp;
#pragma unroll
    for (int i = 0; i < 16; ++i) tmp.u[i] = f2bf(tile[cs + i][pl]);
    u16* dst = seq + ((size_t)(n * HW + pb + pl)) * CCH + cb + cs;
    *(uint4*)dst = tmp.v[0];
    *(uint4*)(dst + 8) = tmp.v[1];
  }
}

// ---------------- QKV GEMM -> scatter Q(scaled)/K/Vt ----------------
__global__ __launch_bounds__(256) void k_qkv(
    const u16* __restrict__ seq, const u16* __restrict__ w,
    u16* __restrict__ Q, u16* __restrict__ K, u16* __restrict__ Vt) {
  __shared__ __attribute__((aligned(16))) u16 As[64 * 32];
  __shared__ __attribute__((aligned(16))) u16 Bs[64 * 32];
  int Rb = blockIdx.x * 64, Cb = blockIdx.y * 64;
  int t = threadIdx.x, lane = t & 63, wv = t >> 6;
  int wr = (wv >> 1) * 32, wc = (wv & 1) * 32;
  f32x4 acc[2][2] = {};
  for (int kb = 0; kb < CCH; kb += 32) {
    {
      int r = t >> 2, kc = t & 3;
      uint4 v = *(const uint4*)(seq + ((size_t)(Rb + r)) * CCH + kb + kc * 8);
      *(uint4*)((char*)As + r * 64 + ((kc * 16) ^ ((r & 3) << 4))) = v;
    }
    {
      int k = t >> 3, jc = (t & 7) * 8;
      union { u16 u[8]; uint4 v; } tmp;
      tmp.v = *(const uint4*)(w + ((size_t)(kb + k)) * 768 + Cb + jc);
#pragma unroll
      for (int i2 = 0; i2 < 8; ++i2) {
        int j = jc + i2;
        *(u16*)((char*)Bs + j * 64 + ((k * 2) ^ ((j & 3) << 4))) = tmp.u[i2];
      }
    }
    __syncthreads();
    bf16x8 af[2], bfr[2];
#pragma unroll
    for (int f = 0; f < 2; ++f) {
      int row = wr + f * 16 + (lane & 15);
      af[f] = *(const bf16x8*)((const char*)As + row * 64 +
                               (((lane >> 4) * 16) ^ ((row & 3) << 4)));
      int col = wc + f * 16 + (lane & 15);
      bfr[f] = *(const bf16x8*)((const char*)Bs + col * 64 +
                                (((lane >> 4) * 16) ^ ((col & 3) << 4)));
    }
#pragma unroll
    for (int i2 = 0; i2 < 2; ++i2)
#pragma unroll
      for (int j2 = 0; j2 < 2; ++j2)
        acc[i2][j2] = __builtin_amdgcn_mfma_f32_16x16x32_bf16(af[i2], bfr[j2], acc[i2][j2], 0, 0, 0);
    __syncthreads();
  }
#pragma unroll
  for (int i2 = 0; i2 < 2; ++i2)
#pragma unroll
    for (int j2 = 0; j2 < 2; ++j2)
#pragma unroll
      for (int e = 0; e < 4; ++e) {
        int R = Rb + wr + i2 * 16 + (lane >> 4) * 4 + e;
        int cg = Cb + wc + j2 * 16 + (lane & 15);
        int p = R & (HW - 1);
        int head = p >> 10, mq = p & 1023;
        int qn = mq * 4 + cg / 192, tt = cg % 192;
        int nhx = (R >> 12) * HEADS + head;
        float a = acc[i2][j2][e];
        if (tt < 64)
          Q[((size_t)nhx * SLEN + qn) * DH + tt] = f2bf(a * QSCALE);
        else if (tt < 128)
          K[((size_t)nhx * SLEN + qn) * DH + tt - 64] = f2bf(a);
        else
          Vt[(size_t)nhx * SLEN * DH + (size_t)(tt - 128) * SLEN + qn] = f2bf(a);
      }
}

// ---------------- flash attention: R3 structure (best measured, 164us) ----------------
// 4 waves, 64 q shared per block's q-range, kvsplit4; K+V loaded at tile top
// (no pipelining, no launch_bounds cap -> no spills). Plus the three verified
// deltas: XCD-chunked swizzle (FETCH 70->20MB), gate-first softmax (no
// cross-lane ops in common path), s_setprio around MFMA clusters.
__global__ __launch_bounds__(256, 2) void k_attn(
    const u16* __restrict__ Q, const u16* __restrict__ K,
    const u16* __restrict__ Vt, u16* __restrict__ O) {
  __shared__ __attribute__((aligned(16))) char smem[32768 + 2048];
  float* mlA = (float*)(smem + 32768);         // [slot4][qf4][row16] m
  float* mlB = (float*)(smem + 32768 + 1024);  // [slot4][qf4][row16] l
  // XCD-chunked swizzle: each XCD gets a contiguous 128-block chunk
  // (= 2 heads' K/V -> fits its 4MB L2). Verified: FETCH 70->20 MB.
  int bid = blockIdx.x;
  int wid = (bid & 7) * 128 + (bid >> 3);
  int nh = wid >> 6;
  int q0 = (wid & 63) * 64;
  int t = threadIdx.x, lane = t & 63, w = t >> 6;
  int l15 = lane & 15, g = lane >> 4;
  size_t base = (size_t)nh * SLEN * DH;
  char* Ps = smem + w * 8192;  // [64 q][64 kv] bf16, swizzled
  int swz = (l15 & 7) << 4;

  // Q fragments (B-operand: col = q = l15, k = d)
  bf16x8 qv[4][2];
#pragma unroll
  for (int qf = 0; qf < 4; ++qf) {
    const u16* qp = Q + base + (size_t)(q0 + qf * 16 + l15) * DH + g * 8;
    qv[qf][0] = *(const bf16x8*)qp;
    qv[qf][1] = *(const bf16x8*)(qp + 32);
  }

  f32x4 o[4][4] = {};
  float m[4] = {NEG_INF, NEG_INF, NEG_INF, NEG_INF};
  float lsum[4] = {0.f, 0.f, 0.f, 0.f};

  const u16* Kptr = K + base + (size_t)l15 * DH + g * 8;
  const u16* Vptr = Vt + base + (size_t)l15 * SLEN + g * 8;

  const int TILES = SLEN / 64 / 4;  // 16 per wave
  int kvBase = w * TILES * 64;
  for (int tt = 0; tt < TILES; ++tt) {
    int kv0 = kvBase + tt * 64;
    // K fragments (A-operand: row = kv = cf*16 + l15, k = d)
    bf16x8 kf[4][2], vf[4][2];
#pragma unroll
    for (int cf = 0; cf < 4; ++cf) {
      const u16* kp = Kptr + (size_t)(kv0 + cf * 16) * DH;
      kf[cf][0] = *(const bf16x8*)kp;
      kf[cf][1] = *(const bf16x8*)(kp + 32);
    }
    // V^T fragments (B-operand for PV: col = d = df*16 + l15, k = kv)
#pragma unroll
    for (int df = 0; df < 4; ++df) {
      const u16* vp = Vptr + (size_t)(df * 16) * SLEN + kv0;
      vf[df][0] = *(const bf16x8*)vp;
      vf[df][1] = *(const bf16x8*)(vp + 32);
    }
#pragma unroll
    for (int qf = 0; qf < 4; ++qf) {
      f32x4 st[4];
      __builtin_amdgcn_s_setprio(1);
#pragma unroll
      for (int cf = 0; cf < 4; ++cf) {
        f32x4 a = {};
        a = __builtin_amdgcn_mfma_f32_16x16x32_bf16(kf[cf][0], qv[qf][0], a, 0, 0, 0);
        a = __builtin_amdgcn_mfma_f32_16x16x32_bf16(kf[cf][1], qv[qf][1], a, 0, 0, 0);
        st[cf] = a;
      }
      __builtin_amdgcn_s_setprio(0);
      // gate-first: in-lane max tree, __any gate BEFORE any exp/cross-lane work
      float mx0 = fmaxf(fmaxf(st[0][0], st[0][1]), fmaxf(st[0][2], st[0][3]));
      float mx1 = fmaxf(fmaxf(st[1][0], st[1][1]), fmaxf(st[1][2], st[1][3]));
      float mx2 = fmaxf(fmaxf(st[2][0], st[2][1]), fmaxf(st[2][2], st[2][3]));
      float mx3 = fmaxf(fmaxf(st[3][0], st[3][1]), fmaxf(st[3][2], st[3][3]));
      float stmax = fmaxf(fmaxf(mx0, mx1), fmaxf(mx2, mx3));
      if (__any(stmax > m[qf] + 8.0f)) {
        // rare path (first tile + material max growth): true row max + rescale
        float mx = fmaxf(stmax, __shfl_xor(stmax, 16));
        mx = fmaxf(mx, __shfl_xor(mx, 32));
        float mn = fmaxf(m[qf], mx);
        float al = exp2f(m[qf] - mn);
        m[qf] = mn;
        lsum[qf] *= al;
#pragma unroll
        for (int e = 0; e < 4; ++e) {
          float ae = __shfl(al, (lane & 48) | (((lane >> 4) << 2) + e));
#pragma unroll
          for (int df = 0; df < 4; ++df) o[qf][df][e] *= ae;
        }
      }
      float mq = m[qf];
      f32x4 lsv = {0.f, 0.f, 0.f, 0.f};
#pragma unroll
      for (int cf = 0; cf < 4; ++cf) {
        union { __bf16 h[4]; uint2 v; } pk;
#pragma unroll
        for (int e = 0; e < 4; ++e) {
          float p = exp2f(st[cf][e] - mq);
          lsv[e] += p;
          pk.h[e] = (__bf16)p;
        }
        *(uint2*)(Ps + (qf * 16 + l15) * 128 + ((cf * 32 + g * 8) ^ swz)) = pk.v;
      }
      lsum[qf] += lsv[0] + lsv[1] + lsv[2] + lsv[3];
    }
    // PV: A = P (from per-wave LDS), B = V^T fragments
#pragma unroll
    for (int qf = 0; qf < 4; ++qf) {
#pragma unroll
      for (int ks = 0; ks < 2; ++ks) {
        bf16x8 pa = *(const bf16x8*)(Ps + (qf * 16 + l15) * 128 + ((ks * 64 + g * 16) ^ swz));
        __builtin_amdgcn_s_setprio(1);
#pragma unroll
        for (int df = 0; df < 4; ++df)
          o[qf][df] = __builtin_amdgcn_mfma_f32_16x16x32_bf16(pa, vf[df][ks], o[qf][df], 0, 0, 0);
        __builtin_amdgcn_s_setprio(0);
      }
    }
  }

  // finalize per-wave state: reduce l across g, convert m/l to C-frag layout
#pragma unroll
  for (int qf = 0; qf < 4; ++qf) {
    lsum[qf] += __shfl_xor(lsum[qf], 16);
    lsum[qf] += __shfl_xor(lsum[qf], 32);
  }
  f32x4 me[4], le[4];
#pragma unroll
  for (int qf = 0; qf < 4; ++qf)
#pragma unroll
    for (int e = 0; e < 4; ++e) {
      int idx = (lane & 48) | (((lane >> 4) & 3) << 2) | e;
      me[qf][e] = __shfl(m[qf], idx);
      le[qf][e] = __shfl(lsum[qf], idx);
    }

  auto publish = [&](char* reg, int s) {
#pragma unroll
    for (int qf = 0; qf < 4; ++qf) {
#pragma unroll
      for (int df = 0; df < 4; ++df) {
        int d = df * 16 + l15;
        *(f32x4*)(reg + ((d * 256 + qf * 64 + g * 16) ^ ((d & 7) << 4))) = o[qf][df];
      }
      if (l15 == 0) {
        *(f32x4*)&mlA[(s * 4 + qf) * 16 + g * 4] = me[qf];
        *(f32x4*)&mlB[(s * 4 + qf) * 16 + g * 4] = le[qf];
      }
    }
  };
  auto merge = [&](char* reg, int s) {
#pragma unroll
    for (int qf = 0; qf < 4; ++qf) {
      f32x4 mp = *(f32x4*)&mlA[(s * 4 + qf) * 16 + g * 4];
      f32x4 lp = *(f32x4*)&mlB[(s * 4 + qf) * 16 + g * 4];
      f32x4 op[4];
#pragma unroll
      for (int df = 0; df < 4; ++df) {
        int d = df * 16 + l15;
        op[df] = *(f32x4*)(reg + ((d * 256 + qf * 64 + g * 16) ^ ((d & 7) << 4)));
      }
#pragma unroll
      for (int e = 0; e < 4; ++e) {
        float mf = fmaxf(me[qf][e], mp[e]);
        float as = exp2f(me[qf][e] - mf), ap = exp2f(mp[e] - mf);
        le[qf][e] = le[qf][e] * as + lp[e] * ap;
        me[qf][e] = mf;
#pragma unroll
        for (int df = 0; df < 4; ++df)
          o[qf][df][e] = o[qf][df][e] * as + op[df][e] * ap;
      }
    }
  };

  __syncthreads();  // done with Ps
  if (w == 1) publish(smem, 1);
  if (w == 3) publish(smem + 16384, 3);
  __syncthreads();
  if (w == 0) merge(smem, 1);
  if (w == 2) merge(smem + 16384, 3);
  __syncthreads();
  if (w == 2) publish(smem, 2);
  __syncthreads();
  if (w == 0) {
    merge(smem, 2);
    int n = nh >> 2, head = nh & 3;
#pragma unroll
    for (int qf = 0; qf < 4; ++qf) {
      f32x4 rinv;
#pragma unroll
      for (int e = 0; e < 4; ++e) rinv[e] = 1.f / le[qf][e];
#pragma unroll
      for (int df = 0; df < 4; ++df) {
        int d = df * 16 + l15;
#pragma unroll
        for (int e = 0; e < 4; ++e) {
          int qn = q0 + qf * 16 + g * 4 + e;
          size_t off = (((size_t)n * HW) + head * 1024 + (qn >> 2)) * CCH + (qn & 3) * DH + d;
          O[off] = f2bf(o[qf][df][e] * rinv[e]);
        }
      }
    }
  }
}

// ---------------- proj GEMM + bias + transpose to (n, c, hw) fp32 ----------------
__global__ __launch_bounds__(256) void k_proj(
    const u16* __restrict__ A, const u16* __restrict__ W,
    const float* __restrict__ bias, float* __restrict__ out) {
  __shared__ __attribute__((aligned(16))) u16 As[64 * 32];
  __shared__ __attribute__((aligned(16))) u16 Bs[64 * 32];
  int Rb = blockIdx.x * 64, Cb = blockIdx.y * 64;
  int t = threadIdx.x, lane = t & 63, wv = t >> 6;
  int wr = (wv >> 1) * 32, wc = (wv & 1) * 32;
  f32x4 acc[2][2] = {};
  for (int kb = 0; kb < CCH; kb += 32) {
    {
      int r = t >> 2, kc = t & 3;
      uint4 v = *(const uint4*)(A + ((size_t)(Rb + r)) * CCH + kb + kc * 8);
      *(uint4*)((char*)As + r * 64 + ((kc * 16) ^ ((r & 3) << 4))) = v;
    }
    {
      int k = t >> 3, jc = (t & 7) * 8;
      union { u16 u[8]; uint4 v; } tmp;
      tmp.v = *(const uint4*)(W + ((size_t)(kb + k)) * CCH + Cb + jc);
#pragma unroll
      for (int i2 = 0; i2 < 8; ++i2) {
        int j = jc + i2;
        *(u16*)((char*)Bs + j * 64 + ((k * 2) ^ ((j & 3) << 4))) = tmp.u[i2];
      }
    }
    __syncthreads();
    bf16x8 af[2], bfr[2];
#pragma unroll
    for (int f = 0; f < 2; ++f) {
      int row = wr + f * 16 + (lane & 15);
      af[f] = *(const bf16x8*)((const char*)As + row * 64 +
                               (((lane >> 4) * 16) ^ ((row & 3) << 4)));
      int col = wc + f * 16 + (lane & 15);
      bfr[f] = *(const bf16x8*)((const char*)Bs + col * 64 +
                                (((lane >> 4) * 16) ^ ((col & 3) << 4)));
    }
#pragma unroll
    for (int i2 = 0; i2 < 2; ++i2)
#pragma unroll
      for (int j2 = 0; j2 < 2; ++j2)
        acc[i2][j2] = __builtin_amdgcn_mfma_f32_16x16x32_bf16(af[i2], bfr[j2], acc[i2][j2], 0, 0, 0);
    __syncthreads();
  }
#pragma unroll
  for (int i2 = 0; i2 < 2; ++i2)
#pragma unroll
    for (int j2 = 0; j2 < 2; ++j2)
#pragma unroll
      for (int e = 0; e < 4; ++e) {
        int R = Rb + wr + i2 * 16 + (lane >> 4) * 4 + e;
        int cg = Cb + wc + j2 * 16 + (lane & 15);
        out[((size_t)((R >> 12) * CCH + cg)) * HW + (R & (HW - 1))] =
            acc[i2][j2][e] + bias[cg];
      }
}

extern "C" void kernel_launch(void* const* d_in, const int* in_sizes, int n_in,
                              void* d_out, int out_size, void* d_ws, size_t ws_size,
                              hipStream_t stream) {
  (void)in_sizes; (void)n_in; (void)out_size; (void)ws_size;
  const float* x      = (const float*)d_in[0];
  const float* gamma  = (const float*)d_in[1];
  const float* beta   = (const float*)d_in[2];
  const float* qkv_w  = (const float*)d_in[3];
  const float* proj_w = (const float*)d_in[4];
  const float* proj_b = (const float*)d_in[5];

  char* ws = (char*)d_ws;
  size_t off = 0;
  float* ab = (float*)(ws + off); off += 4096;
  u16* seq  = (u16*)(ws + off);  off += (size_t)NB * HW * CCH * 2;       // 8 MB
  u16* qwb  = (u16*)(ws + off);  off += (size_t)CCH * 3 * CCH * 2;      // 384 KB
  u16* pwb  = (u16*)(ws + off);  off += (size_t)CCH * CCH * 2;          // 128 KB
  u16* Qb   = (u16*)(ws + off);  off += (size_t)NB * HEADS * SLEN * DH * 2;  // 8 MB
  u16* Kb   = (u16*)(ws + off);  off += (size_t)NB * HEADS * SLEN * DH * 2;
  u16* Vtb  = (u16*)(ws + off);  off += (size_t)NB * HEADS * SLEN * DH * 2;
  u16* oseq = (u16*)(ws + off);  off += (size_t)NB * HW * CCH * 2;

  k_pre<<<384, 256, 0, stream>>>(x, gamma, beta, qkv_w, proj_w, ab, qwb, pwb);
  k_seq<<<dim3(HW / 64, CCH / 64, NB), 256, 0, stream>>>(x, ab, seq);
  k_qkv<<<dim3((NB * HW) / 64, 768 / 64), 256, 0, stream>>>(seq, qwb, Qb, Kb, Vtb);
  k_attn<<<1024, 256, 0, stream>>>(Qb, Kb, Vtb, oseq);
  k_proj<<<dim3((NB * HW) / 64, CCH / 64), 256, 0, stream>>>(oseq, pwb, proj_b, (float*)d_out);
}